// Round 17
// baseline (282.405 us; speedup 1.0000x reference)
//
#include <hip/hip_runtime.h>
#include <math.h>

#define HW_  16384
#define Q_   200
#define C_   1024
#define L_   16584   // Q_ + HW_
#define NH_  16
#define HD_  64
#define CAP  512
#define KSPLIT 8
#define KCH  (HW_ / KSPLIT)   // 2048
#define ASPLIT 4
#define SK   4                // split-K for small projections

typedef __attribute__((ext_vector_type(8))) __bf16 bf16x8;
typedef __attribute__((ext_vector_type(8))) unsigned short u16x8;
typedef __attribute__((ext_vector_type(4))) unsigned short u16x4;
typedef __attribute__((ext_vector_type(4))) float f32x4;

__device__ inline unsigned short f2bf(float f) {
  unsigned int u = __float_as_uint(f);
  u += 0x7fff + ((u >> 16) & 1);   // round-to-nearest-even
  return (unsigned short)(u >> 16);
}
__device__ inline float bf2f(unsigned short u) {
  return __uint_as_float((unsigned int)u << 16);
}

// LDS XOR swizzle (T2): LDS[row][slot] holds global[row][slot ^ ((row>>1)&3)].
// Staged via pre-swizzled global source; ds_read uses slot fq ^ ((fr>>1)&3).

// ---------------------------------------------------------------------------
// Fused: sigmoid + bf16 cast + row-sum w[q] + allowed-index compaction.
__global__ __launch_bounds__(256) void k_sig_compact(const float* __restrict__ masks,
                                                     unsigned short* __restrict__ msigbf,
                                                     float* __restrict__ w,
                                                     int* __restrict__ cnt,
                                                     int* __restrict__ idxg) {
  int q = blockIdx.x;
  int tid = threadIdx.x;
  unsigned short* obf = msigbf + (size_t)q * HW_;
  if (q >= Q_) {
    u16x4 z = {0, 0, 0, 0};
    for (int i = tid; i < HW_ / 4; i += 256) *(u16x4*)&obf[i * 4] = z;
    return;
  }
  const float* mrow = masks + (size_t)q * HW_;
  const int base = tid * 64;
  unsigned long long bits = 0;
  float s = 0.f;
  #pragma unroll
  for (int j4 = 0; j4 < 16; j4++) {
    float4 v = *(const float4*)&mrow[base + j4 * 4];
    float sg0 = 1.f / (1.f + expf(-v.x));
    float sg1 = 1.f / (1.f + expf(-v.y));
    float sg2 = 1.f / (1.f + expf(-v.z));
    float sg3 = 1.f / (1.f + expf(-v.w));
    u16x4 o = {f2bf(sg0), f2bf(sg1), f2bf(sg2), f2bf(sg3)};
    *(u16x4*)&obf[base + j4 * 4] = o;
    s += sg0 + sg1 + sg2 + sg3;
    if (sg0 > 0.9f) bits |= 1ull << (j4 * 4 + 0);
    if (sg1 > 0.9f) bits |= 1ull << (j4 * 4 + 1);
    if (sg2 > 0.9f) bits |= 1ull << (j4 * 4 + 2);
    if (sg3 > 0.9f) bits |= 1ull << (j4 * 4 + 3);
  }
  int my = __popcll(bits);

  __shared__ float red[256];
  __shared__ int sc[256];
  red[tid] = s;
  sc[tid] = my;
  __syncthreads();
  for (int off = 128; off > 0; off >>= 1) {
    if (tid < off) red[tid] += red[tid + off];
    __syncthreads();
  }
  if (tid == 0) w[q] = red[0];
  for (int off = 1; off < 256; off <<= 1) {
    int v = sc[tid];
    int add = (tid >= off) ? sc[tid - off] : 0;
    __syncthreads();
    sc[tid] = v + add;
    __syncthreads();
  }
  int excl = sc[tid] - my;
  int total = sc[255];
  int* orow = idxg + (size_t)q * CAP;
  int off = 1 + excl;  // slot 0 = self
  for (int j = 0; j < 64; j++) {
    if ((bits >> j) & 1ull) {
      if (off < CAP) orow[off] = Q_ + base + j;
      off++;
    }
  }
  if (tid == 0) {
    orow[0] = q;
    int c = 1 + total;
    cnt[q] = c < CAP ? c : CAP;
  }
}

// ---------------------------------------------------------------------------
// x [C][HW] fp32 -> xbf [C][HW] bf16 (same layout) + seqbf pixel rows (transposed)
__global__ __launch_bounds__(256) void k_xcast(const float* __restrict__ x,
                                               unsigned short* __restrict__ xbf,
                                               unsigned short* __restrict__ seqbf) {
  __shared__ float t[32][33];
  int l0 = blockIdx.x * 32, c0 = blockIdx.y * 32;
  int tx = threadIdx.x, ty = threadIdx.y;  // (32,8)
  #pragma unroll
  for (int i = 0; i < 32; i += 8) {
    float v = x[(size_t)(c0 + ty + i) * HW_ + l0 + tx];
    t[ty + i][tx] = v;
    xbf[(size_t)(c0 + ty + i) * HW_ + l0 + tx] = f2bf(v);
  }
  __syncthreads();
  #pragma unroll
  for (int i = 0; i < 32; i += 8)
    seqbf[(size_t)(Q_ + l0 + ty + i) * C_ + c0 + tx] = f2bf(t[tx][ty + i]);
}

// ---------------------------------------------------------------------------
// Four weight casts in one launch. blockIdx.y selects tensor.
__global__ __launch_bounds__(256) void k_cast4(const float* __restrict__ s0,
                                               const float* __restrict__ s1,
                                               const float* __restrict__ s2,
                                               const float* __restrict__ s3,
                                               unsigned short* __restrict__ d0,
                                               unsigned short* __restrict__ d1,
                                               unsigned short* __restrict__ d2,
                                               unsigned short* __restrict__ d3) {
  const float* src = (blockIdx.y == 0) ? s0 : (blockIdx.y == 1) ? s1
                     : (blockIdx.y == 2) ? s2 : s3;
  unsigned short* dst = (blockIdx.y == 0) ? d0 : (blockIdx.y == 1) ? d1
                        : (blockIdx.y == 2) ? d2 : d3;
  int i = (blockIdx.x * 256 + threadIdx.x) * 4;
  float4 v = *(const float4*)&src[i];
  u16x4 o = {f2bf(v.x), f2bf(v.y), f2bf(v.z), f2bf(v.w)};
  *(u16x4*)&dst[i] = o;
}

#define GBM 128
#define GBN 128
#define GBK 32

// ---------------------------------------------------------------------------
// Fused K+V projection GEMM. 512 threads = 8 waves; waves 0-3: K tile (2x2),
// waves 4-7: V tile. A staged once per K-step for both outputs.
// 3-buffer, SINGLE barrier per K-step. T2 swizzle + T5 setprio.
__global__ __launch_bounds__(512) void k_gemm_kv(const unsigned short* __restrict__ A,
                                                 const unsigned short* __restrict__ Bk,
                                                 const unsigned short* __restrict__ Bv,
                                                 const float* __restrict__ bk,
                                                 const float* __restrict__ bv,
                                                 unsigned short* __restrict__ Ko,
                                                 unsigned short* __restrict__ Vo,
                                                 int M, int K) {
  __shared__ __attribute__((aligned(16))) unsigned short smem[3][3 * GBM * GBK]; // 72 KB
  int w = blockIdx.x;
  int nbm = gridDim.x >> 3;                  // 130
  int t = (w >> 3) + (w & 7) * nbm;          // contiguous t per XCD
  int bm = (t >> 3) * GBM;
  int bn = (t & 7) * GBN;
  int tid = threadIdx.x;
  int wid = tid >> 6, lane = tid & 63;
  int w2 = wid & 3;
  int wr = w2 >> 1, wc = w2 & 1;
  int fq = lane >> 4, fr = lane & 15;
  int srow = lane >> 2;
  int scol = (((lane & 3) ^ ((lane >> 3) & 3)) * 8);   // pre-swizzled source col
  int sslot = (fq ^ ((fr >> 1) & 3)) * 8;              // swizzled read slot
  int boff = (wid < 4) ? GBM * GBK : 2 * GBM * GBK;

  auto stage = [&](int buf, int k0) {
    #pragma unroll
    for (int i = 0; i < 3; i++) {
      int ci = wid * 3 + i;                  // 0..23 chunks of 1 KB (16 rows)
      const unsigned short* src;
      if (ci < 8) {
        int gA = bm + ci * 16 + srow; if (gA > M - 1) gA = M - 1;
        src = A + (size_t)gA * K + k0 + scol;
      } else if (ci < 16) {
        src = Bk + (size_t)(bn + (ci - 8) * 16 + srow) * K + k0 + scol;
      } else {
        src = Bv + (size_t)(bn + (ci - 16) * 16 + srow) * K + k0 + scol;
      }
      __builtin_amdgcn_global_load_lds(
          (const __attribute__((address_space(1))) void*)src,
          (__attribute__((address_space(3))) void*)((char*)&smem[buf][0] + ci * 1024),
          16, 0, 0);
    }
  };

  f32x4 acc[4][4] = {};
  const int NT = K / GBK;                    // 32
  stage(0, 0);
  stage(1, GBK);
  for (int it = 0; it < NT; it++) {
    int cur = it % 3;
    asm volatile("" ::: "memory");
    __builtin_amdgcn_s_barrier();            // all compute(it-1) reads done
    asm volatile("" ::: "memory");
    if (it + 2 < NT) {
      stage((it + 2) % 3, (it + 2) * GBK);
      asm volatile("s_waitcnt vmcnt(6)" ::: "memory");
    } else if (it + 1 < NT) {
      asm volatile("s_waitcnt vmcnt(3)" ::: "memory");
    } else {
      asm volatile("s_waitcnt vmcnt(0)" ::: "memory");
    }
    const unsigned short (*As)[GBK]  = (const unsigned short (*)[GBK])(&smem[cur][0]);
    const unsigned short (*Bts)[GBK] = (const unsigned short (*)[GBK])(&smem[cur][0] + boff);
    bf16x8 af[4], bfr[4];
    #pragma unroll
    for (int mi = 0; mi < 4; mi++)
      af[mi] = *(const bf16x8*)&As[wr * 64 + mi * 16 + fr][sslot];
    #pragma unroll
    for (int ni = 0; ni < 4; ni++)
      bfr[ni] = *(const bf16x8*)&Bts[wc * 64 + ni * 16 + fr][sslot];
    __builtin_amdgcn_s_setprio(1);
    #pragma unroll
    for (int mi = 0; mi < 4; mi++)
      #pragma unroll
      for (int ni = 0; ni < 4; ni++)
        acc[mi][ni] = __builtin_amdgcn_mfma_f32_16x16x32_bf16(bfr[ni], af[mi], acc[mi][ni], 0, 0, 0);
    __builtin_amdgcn_s_setprio(0);
  }
  // Swapped layout: lane value j -> n = bn + wc*64 + ni*16 + fq*4 + j,
  //                 m = bm + wr*64 + mi*16 + fr.  (mi outer: line-adjacent stores)
  const float* bias = (wid < 4) ? bk : bv;
  unsigned short* Cout = (wid < 4) ? Ko : Vo;
  #pragma unroll
  for (int mi = 0; mi < 4; mi++) {
    int m = bm + wr * 64 + mi * 16 + fr;
    if (m >= M) continue;
    #pragma unroll
    for (int ni = 0; ni < 4; ni++) {
      int n0 = bn + wc * 64 + ni * 16 + fq * 4;
      float4 b4 = *(const float4*)&bias[n0];
      u16x4 o = {f2bf(acc[mi][ni][0] + b4.x), f2bf(acc[mi][ni][1] + b4.y),
                 f2bf(acc[mi][ni][2] + b4.z), f2bf(acc[mi][ni][3] + b4.w)};
      *(u16x4*)&Cout[(size_t)m * C_ + n0] = o;
    }
  }
}

// ---------------------------------------------------------------------------
// Split-K mean GEMM v2: single 256-row A tile (msigbf has exactly 256 rows,
// zero-padded), 512 threads = 8 waves (wr = wid>>1 over 4x64 rows, wc = wid&1
// over 2x64 cols). B (xbf) tile staged ONCE per (bn,kc). 2-phase dbuf + T2.
__global__ __launch_bounds__(512) void k_gemm_meank(const unsigned short* __restrict__ A,
                                                    const unsigned short* __restrict__ B,
                                                    float* __restrict__ partial) {
  __shared__ __attribute__((aligned(16))) unsigned short As[2][256][GBK];  // 32 KB
  __shared__ __attribute__((aligned(16))) unsigned short Bs[2][GBN][GBK];  // 16 KB
  int bn = blockIdx.x * GBN;
  int kc = blockIdx.z;
  int tid = threadIdx.x;
  int wid = tid >> 6, lane = tid & 63;
  int wr = wid >> 1, wc = wid & 1;
  int fq = lane >> 4, fr = lane & 15;
  int srow = lane >> 2;
  int scol = (((lane & 3) ^ ((lane >> 3) & 3)) * 8);
  int sslot = (fq ^ ((fr >> 1) & 3)) * 8;

  auto stage = [&](int buf, int k0) {
    #pragma unroll
    for (int i = 0; i < 3; i++) {
      int ci = wid * 3 + i;                  // 0..23: 16 A-chunks, 8 B-chunks
      const unsigned short* src;
      char* dst;
      if (ci < 16) {
        src = A + (size_t)(ci * 16 + srow) * HW_ + k0 + scol;
        dst = (char*)&As[buf][0][0] + ci * 1024;
      } else {
        src = B + (size_t)(bn + (ci - 16) * 16 + srow) * HW_ + k0 + scol;
        dst = (char*)&Bs[buf][0][0] + (ci - 16) * 1024;
      }
      __builtin_amdgcn_global_load_lds(
          (const __attribute__((address_space(1))) void*)src,
          (__attribute__((address_space(3))) void*)dst, 16, 0, 0);
    }
  };

  f32x4 acc[4][4] = {};
  int kbeg = kc * KCH;
  const int NT = KCH / GBK;
  stage(0, kbeg);
  __syncthreads();
  int cur = 0;
  for (int it = 0; it < NT; it++) {
    if (it + 1 < NT) stage(cur ^ 1, kbeg + (it + 1) * GBK);
    bf16x8 af[4], bfr[4];
    #pragma unroll
    for (int mi = 0; mi < 4; mi++)
      af[mi] = *(const bf16x8*)&As[cur][wr * 64 + mi * 16 + fr][sslot];
    #pragma unroll
    for (int ni = 0; ni < 4; ni++)
      bfr[ni] = *(const bf16x8*)&Bs[cur][wc * 64 + ni * 16 + fr][sslot];
    #pragma unroll
    for (int mi = 0; mi < 4; mi++)
      #pragma unroll
      for (int ni = 0; ni < 4; ni++)
        acc[mi][ni] = __builtin_amdgcn_mfma_f32_16x16x32_bf16(bfr[ni], af[mi], acc[mi][ni], 0, 0, 0);
    __syncthreads();
    cur ^= 1;
  }
  #pragma unroll
  for (int mi = 0; mi < 4; mi++) {
    int m = wr * 64 + mi * 16 + fr;
    #pragma unroll
    for (int ni = 0; ni < 4; ni++) {
      int n0 = bn + wc * 64 + ni * 16 + fq * 4;
      *(f32x4*)&partial[((size_t)kc * 256 + m) * C_ + n0] = acc[mi][ni];
    }
  }
}

// ---------------------------------------------------------------------------
// mean = (sum of partials) / (w + 1e-3) -> seqbf rows 0..Q-1 (bf16)
__global__ __launch_bounds__(256) void k_mean_reduce(const float* __restrict__ partial,
                                                     const float* __restrict__ w,
                                                     unsigned short* __restrict__ seqbf) {
  int m = blockIdx.x;  // 0..Q_-1
  float rs = 1.f / (w[m] + 0.001f);
  for (int n = threadIdx.x; n < C_; n += 256) {
    float s = 0.f;
    #pragma unroll
    for (int kc = 0; kc < KSPLIT; kc++)
      s += partial[((size_t)kc * 256 + m) * C_ + n];
    seqbf[(size_t)m * C_ + n] = f2bf(s * rs);
  }
}

// ---------------------------------------------------------------------------
// Split-K bf16 MFMA GEMM for small-M projections v2: single 256-row A tile
// (clamped reads), 512 threads = 8 waves. 2-phase dbuf + T2 swizzle.
__global__ __launch_bounds__(512) void k_gemm_splitk_bf(const unsigned short* __restrict__ A,
                                                        const unsigned short* __restrict__ B,
                                                        float* __restrict__ partial,
                                                        int M, int K) {
  __shared__ __attribute__((aligned(16))) unsigned short As[2][256][GBK];  // 32 KB
  __shared__ __attribute__((aligned(16))) unsigned short Bs[2][GBN][GBK];  // 16 KB
  int bn = blockIdx.x * GBN;
  int kc = blockIdx.z;
  int kchunk = K / SK;
  int tid = threadIdx.x;
  int wid = tid >> 6, lane = tid & 63;
  int wr = wid >> 1, wc = wid & 1;
  int fq = lane >> 4, fr = lane & 15;
  int srow = lane >> 2;
  int scol = (((lane & 3) ^ ((lane >> 3) & 3)) * 8);
  int sslot = (fq ^ ((fr >> 1) & 3)) * 8;

  auto stage = [&](int buf, int k0) {
    #pragma unroll
    for (int i = 0; i < 3; i++) {
      int ci = wid * 3 + i;
      const unsigned short* src;
      char* dst;
      if (ci < 16) {
        int gA = ci * 16 + srow; if (gA > M - 1) gA = M - 1;
        src = A + (size_t)gA * K + k0 + scol;
        dst = (char*)&As[buf][0][0] + ci * 1024;
      } else {
        src = B + (size_t)(bn + (ci - 16) * 16 + srow) * K + k0 + scol;
        dst = (char*)&Bs[buf][0][0] + (ci - 16) * 1024;
      }
      __builtin_amdgcn_global_load_lds(
          (const __attribute__((address_space(1))) void*)src,
          (__attribute__((address_space(3))) void*)dst, 16, 0, 0);
    }
  };

  f32x4 acc[4][4] = {};
  int kbeg = kc * kchunk;
  const int NT = kchunk / GBK;
  stage(0, kbeg);
  __syncthreads();
  int cur = 0;
  for (int it = 0; it < NT; it++) {
    if (it + 1 < NT) stage(cur ^ 1, kbeg + (it + 1) * GBK);
    bf16x8 af[4], bfr[4];
    #pragma unroll
    for (int mi = 0; mi < 4; mi++)
      af[mi] = *(const bf16x8*)&As[cur][wr * 64 + mi * 16 + fr][sslot];
    #pragma unroll
    for (int ni = 0; ni < 4; ni++)
      bfr[ni] = *(const bf16x8*)&Bs[cur][wc * 64 + ni * 16 + fr][sslot];
    #pragma unroll
    for (int mi = 0; mi < 4; mi++)
      #pragma unroll
      for (int ni = 0; ni < 4; ni++)
        acc[mi][ni] = __builtin_amdgcn_mfma_f32_16x16x32_bf16(bfr[ni], af[mi], acc[mi][ni], 0, 0, 0);
    __syncthreads();
    cur ^= 1;
  }
  #pragma unroll
  for (int mi = 0; mi < 4; mi++) {
    int m = wr * 64 + mi * 16 + fr;
    #pragma unroll
    for (int ni = 0; ni < 4; ni++) {
      int n0 = bn + wc * 64 + ni * 16 + fq * 4;
      *(f32x4*)&partial[((size_t)kc * 256 + m) * C_ + n0] = acc[mi][ni];
    }
  }
}

// ---------------------------------------------------------------------------
__global__ __launch_bounds__(256) void k_splitk_reduce(const float* __restrict__ partial,
                                                       const float* __restrict__ bias,
                                                       float* __restrict__ outf) {
  int m = blockIdx.x;
  for (int n = threadIdx.x; n < C_; n += 256) {
    float s = 0.f;
    #pragma unroll
    for (int kc = 0; kc < SK; kc++)
      s += partial[((size_t)kc * 256 + m) * C_ + n];
    outf[(size_t)m * C_ + n] = s + bias[n];
  }
}

// ---------------------------------------------------------------------------
// Sparse gather attention, split across ASPLIT blocks per (q,h).
// Score phase: 4 lanes per row (quad shfl reduce) for 4x load parallelism.
__global__ __launch_bounds__(256) void k_attn_split(const float* __restrict__ qb,
                                                    const unsigned short* __restrict__ kb,
                                                    const unsigned short* __restrict__ vb,
                                                    const int* __restrict__ cnt_g,
                                                    const int* __restrict__ idxg,
                                                    float* __restrict__ pmax,
                                                    float* __restrict__ psum,
                                                    float* __restrict__ pacc) {
  int q = blockIdx.x, h = blockIdx.y, sp = blockIdx.z;
  int tid = threadIdx.x;
  int lane = tid & 63, wid = tid >> 6;

  __shared__ float qs[64];
  __shared__ float sc[CAP / ASPLIT];   // 128
  __shared__ int   ls[CAP / ASPLIT];
  __shared__ float wred[4];
  __shared__ float accb[4][64];

  int cnt = cnt_g[q];
  int cq = (cnt + ASPLIT - 1) / ASPLIT;
  int beg = sp * cq;
  int end = beg + cq; if (end > cnt) end = cnt;
  int ns = end - beg; if (ns < 0) ns = 0;

  if (tid < 64) qs[tid] = qb[(size_t)q * C_ + h * HD_ + tid] * 0.125f;
  __syncthreads();

  // scores: row i handled by 4 lanes (16 dims each)
  for (int i0 = 0; i0 < ns; i0 += 64) {
    int i = i0 + (tid >> 2);
    if (i < ns) {
      int sub = tid & 3;
      int l = idxg[(size_t)q * CAP + beg + i];
      const u16x8* kr = (const u16x8*)(kb + (size_t)l * C_ + h * HD_ + sub * 16);
      u16x8 kv0 = kr[0], kv1 = kr[1];
      float s = 0.f;
      #pragma unroll
      for (int e = 0; e < 8; e++) s = fmaf(qs[sub * 16 + e], bf2f(kv0[e]), s);
      #pragma unroll
      for (int e = 0; e < 8; e++) s = fmaf(qs[sub * 16 + 8 + e], bf2f(kv1[e]), s);
      s += __shfl_xor(s, 1);
      s += __shfl_xor(s, 2);
      if (sub == 0) { sc[i] = s; ls[i] = l; }
    }
  }
  __syncthreads();

  float lm = (tid < ns) ? sc[tid] : -INFINITY;
  #pragma unroll
  for (int off = 32; off; off >>= 1) lm = fmaxf(lm, __shfl_xor(lm, off));
  if (lane == 0) wred[wid] = lm;
  __syncthreads();
  float m4 = fmaxf(fmaxf(wred[0], wred[1]), fmaxf(wred[2], wred[3]));

  float e = 0.f;
  if (tid < ns) {
    e = expf(sc[tid] - m4);
    sc[tid] = e;
  }
  float lsum = e;
  #pragma unroll
  for (int off = 32; off; off >>= 1) lsum += __shfl_xor(lsum, off);
  __syncthreads();
  if (lane == 0) wred[wid] = lsum;
  __syncthreads();
  float S4 = wred[0] + wred[1] + wred[2] + wred[3];

  float acc = 0.f;
  for (int j = wid; j < ns; j += 4)
    acc = fmaf(sc[j], bf2f(vb[(size_t)ls[j] * C_ + h * HD_ + lane]), acc);
  accb[wid][lane] = acc;
  __syncthreads();

  int pidx = (q * NH_ + h) * ASPLIT + sp;
  if (tid < 64)
    pacc[(size_t)pidx * 64 + tid] =
        accb[0][tid] + accb[1][tid] + accb[2][tid] + accb[3][tid];
  if (tid == 0) {
    pmax[pidx] = (ns > 0) ? m4 : -INFINITY;
    psum[pidx] = S4;
  }
}

// ---------------------------------------------------------------------------
__global__ __launch_bounds__(64) void k_attn_merge(const float* __restrict__ pmax,
                                                   const float* __restrict__ psum,
                                                   const float* __restrict__ pacc,
                                                   unsigned short* __restrict__ ctxbf) {
  int q = blockIdx.x, h = blockIdx.y;
  int d = threadIdx.x;
  int base = (q * NH_ + h) * ASPLIT;
  float M = -INFINITY;
  #pragma unroll
  for (int s = 0; s < ASPLIT; s++) M = fmaxf(M, pmax[base + s]);
  float S = 0.f, a = 0.f;
  #pragma unroll
  for (int s = 0; s < ASPLIT; s++) {
    float wgt = expf(pmax[base + s] - M);
    S += psum[base + s] * wgt;
    a += pacc[(size_t)(base + s) * 64 + d] * wgt;
  }
  ctxbf[(size_t)q * C_ + h * HD_ + d] = f2bf(a / S);
}

// ---------------------------------------------------------------------------
extern "C" void kernel_launch(void* const* d_in, const int* in_sizes, int n_in,
                              void* d_out, int out_size, void* d_ws, size_t ws_size,
                              hipStream_t stream) {
  const float* x     = (const float*)d_in[0];
  const float* masks = (const float*)d_in[1];
  const float* Wq    = (const float*)d_in[2];
  const float* bq    = (const float*)d_in[3];
  const float* Wk    = (const float*)d_in[4];
  const float* bk    = (const float*)d_in[5];
  const float* Wv    = (const float*)d_in[6];
  const float* bv    = (const float*)d_in[7];
  const float* Wc    = (const float*)d_in[8];
  const float* bc    = (const float*)d_in[9];
  float* out = (float*)d_out;

  char* p = (char*)d_ws;
  auto alloc = [&](size_t bytes) {
    char* r = p;
    p += (bytes + 255) & ~(size_t)255;
    return r;
  };
  float* w       = (float*)alloc(1024);
  float* qbuf    = (float*)alloc((size_t)Q_ * C_ * 4);
  float* partial = (float*)alloc((size_t)KSPLIT * 256 * C_ * 4);
  int*   cnt     = (int*)alloc(1024);
  int*   idxg    = (int*)alloc((size_t)Q_ * CAP * 4);
  float* pmax    = (float*)alloc((size_t)Q_ * NH_ * ASPLIT * 4);
  float* psum    = (float*)alloc((size_t)Q_ * NH_ * ASPLIT * 4);
  float* pacc    = (float*)alloc((size_t)Q_ * NH_ * ASPLIT * 64 * 4);
  unsigned short* msigbf = (unsigned short*)alloc((size_t)256 * HW_ * 2);
  unsigned short* xbf    = (unsigned short*)alloc((size_t)C_ * HW_ * 2);
  unsigned short* seqbf  = (unsigned short*)alloc((size_t)L_ * C_ * 2);
  unsigned short* wkbf   = (unsigned short*)alloc((size_t)C_ * C_ * 2);
  unsigned short* wvbf   = (unsigned short*)alloc((size_t)C_ * C_ * 2);
  unsigned short* wqbf   = (unsigned short*)alloc((size_t)C_ * C_ * 2);
  unsigned short* wcbf   = (unsigned short*)alloc((size_t)C_ * C_ * 2);
  unsigned short* ctxbf  = (unsigned short*)alloc((size_t)256 * C_ * 2);
  unsigned short* kbuf   = (unsigned short*)alloc((size_t)L_ * C_ * 2);
  unsigned short* vbuf   = (unsigned short*)alloc((size_t)L_ * C_ * 2);

  k_sig_compact<<<256, 256, 0, stream>>>(masks, msigbf, w, cnt, idxg);
  k_xcast<<<dim3(HW_ / 32, C_ / 32), dim3(32, 8), 0, stream>>>(x, xbf, seqbf);
  k_cast4<<<dim3(C_ * C_ / 1024, 4), 256, 0, stream>>>(Wk, Wv, Wq, Wc,
                                                       wkbf, wvbf, wqbf, wcbf);
  // mean: split-K MFMA (256-row tile) + reduce (writes seqbf rows 0..Q-1)
  k_gemm_meank<<<dim3(C_ / GBN, 1, KSPLIT), 512, 0, stream>>>(msigbf, xbf, partial);
  k_mean_reduce<<<Q_, 256, 0, stream>>>(partial, w, seqbf);
  // Q projection (bf16 split-K, 256-row tile)
  k_gemm_splitk_bf<<<dim3(C_ / GBN, 1, SK), 512, 0, stream>>>(seqbf, wqbf, partial, Q_, C_);
  k_splitk_reduce<<<Q_, 256, 0, stream>>>(partial, bq, qbuf);
  // Fused K+V projections (bf16 MFMA, bf16 outputs), XCD-local tile order
  k_gemm_kv<<<8 * ((L_ + GBM - 1) / GBM), 512, 0, stream>>>(
      seqbf, wkbf, wvbf, bk, bv, kbuf, vbuf, L_, C_);
  // sparse attention (split + merge -> ctxbf)
  k_attn_split<<<dim3(Q_, NH_, ASPLIT), 256, 0, stream>>>(
      qbuf, kbuf, vbuf, cnt, idxg, pmax, psum, pacc);
  k_attn_merge<<<dim3(Q_, NH_), 64, 0, stream>>>(pmax, psum, pacc, ctxbf);
  // output projection (bf16 split-K, 256-row tile)
  k_gemm_splitk_bf<<<dim3(C_ / GBN, 1, SK), 512, 0, stream>>>(ctxbf, wcbf, partial, Q_, C_);
  k_splitk_reduce<<<Q_, 256, 0, stream>>>(partial, bc, out);
}

// Round 18
// 267.183 us; speedup vs baseline: 1.0570x; 1.0570x over previous
//
#include <hip/hip_runtime.h>
#include <math.h>

#define HW_  16384
#define Q_   200
#define C_   1024
#define L_   16584   // Q_ + HW_
#define NH_  16
#define HD_  64
#define CAP  512
#define KSPLIT 8
#define KCH  (HW_ / KSPLIT)   // 2048
#define ASPLIT 4
#define SK   4                // split-K for small projections

typedef __attribute__((ext_vector_type(8))) __bf16 bf16x8;
typedef __attribute__((ext_vector_type(8))) unsigned short u16x8;
typedef __attribute__((ext_vector_type(4))) unsigned short u16x4;
typedef __attribute__((ext_vector_type(4))) float f32x4;

__device__ inline unsigned short f2bf(float f) {
  unsigned int u = __float_as_uint(f);
  u += 0x7fff + ((u >> 16) & 1);   // round-to-nearest-even
  return (unsigned short)(u >> 16);
}
__device__ inline float bf2f(unsigned short u) {
  return __uint_as_float((unsigned int)u << 16);
}

// LDS XOR swizzle (T2): LDS[row][slot] holds global[row][slot ^ ((row>>1)&3)].
// Staged via pre-swizzled global source; ds_read uses slot fq ^ ((fr>>1)&3).

// ---------------------------------------------------------------------------
// Fused: sigmoid + bf16 cast + row-sum w[q] + allowed-index compaction.
__global__ __launch_bounds__(256) void k_sig_compact(const float* __restrict__ masks,
                                                     unsigned short* __restrict__ msigbf,
                                                     float* __restrict__ w,
                                                     int* __restrict__ cnt,
                                                     int* __restrict__ idxg) {
  int q = blockIdx.x;
  int tid = threadIdx.x;
  unsigned short* obf = msigbf + (size_t)q * HW_;
  if (q >= Q_) {
    u16x4 z = {0, 0, 0, 0};
    for (int i = tid; i < HW_ / 4; i += 256) *(u16x4*)&obf[i * 4] = z;
    return;
  }
  const float* mrow = masks + (size_t)q * HW_;
  const int base = tid * 64;
  unsigned long long bits = 0;
  float s = 0.f;
  #pragma unroll
  for (int j4 = 0; j4 < 16; j4++) {
    float4 v = *(const float4*)&mrow[base + j4 * 4];
    float sg0 = 1.f / (1.f + expf(-v.x));
    float sg1 = 1.f / (1.f + expf(-v.y));
    float sg2 = 1.f / (1.f + expf(-v.z));
    float sg3 = 1.f / (1.f + expf(-v.w));
    u16x4 o = {f2bf(sg0), f2bf(sg1), f2bf(sg2), f2bf(sg3)};
    *(u16x4*)&obf[base + j4 * 4] = o;
    s += sg0 + sg1 + sg2 + sg3;
    if (sg0 > 0.9f) bits |= 1ull << (j4 * 4 + 0);
    if (sg1 > 0.9f) bits |= 1ull << (j4 * 4 + 1);
    if (sg2 > 0.9f) bits |= 1ull << (j4 * 4 + 2);
    if (sg3 > 0.9f) bits |= 1ull << (j4 * 4 + 3);
  }
  int my = __popcll(bits);

  __shared__ float red[256];
  __shared__ int sc[256];
  red[tid] = s;
  sc[tid] = my;
  __syncthreads();
  for (int off = 128; off > 0; off >>= 1) {
    if (tid < off) red[tid] += red[tid + off];
    __syncthreads();
  }
  if (tid == 0) w[q] = red[0];
  for (int off = 1; off < 256; off <<= 1) {
    int v = sc[tid];
    int add = (tid >= off) ? sc[tid - off] : 0;
    __syncthreads();
    sc[tid] = v + add;
    __syncthreads();
  }
  int excl = sc[tid] - my;
  int total = sc[255];
  int* orow = idxg + (size_t)q * CAP;
  int off = 1 + excl;  // slot 0 = self
  for (int j = 0; j < 64; j++) {
    if ((bits >> j) & 1ull) {
      if (off < CAP) orow[off] = Q_ + base + j;
      off++;
    }
  }
  if (tid == 0) {
    orow[0] = q;
    int c = 1 + total;
    cnt[q] = c < CAP ? c : CAP;
  }
}

// ---------------------------------------------------------------------------
// x [C][HW] fp32 -> xbf [C][HW] bf16 (same layout) + seqbf pixel rows (transposed)
__global__ __launch_bounds__(256) void k_xcast(const float* __restrict__ x,
                                               unsigned short* __restrict__ xbf,
                                               unsigned short* __restrict__ seqbf) {
  __shared__ float t[32][33];
  int l0 = blockIdx.x * 32, c0 = blockIdx.y * 32;
  int tx = threadIdx.x, ty = threadIdx.y;  // (32,8)
  #pragma unroll
  for (int i = 0; i < 32; i += 8) {
    float v = x[(size_t)(c0 + ty + i) * HW_ + l0 + tx];
    t[ty + i][tx] = v;
    xbf[(size_t)(c0 + ty + i) * HW_ + l0 + tx] = f2bf(v);
  }
  __syncthreads();
  #pragma unroll
  for (int i = 0; i < 32; i += 8)
    seqbf[(size_t)(Q_ + l0 + ty + i) * C_ + c0 + tx] = f2bf(t[tx][ty + i]);
}

// ---------------------------------------------------------------------------
// Four weight casts in one launch. blockIdx.y selects tensor.
__global__ __launch_bounds__(256) void k_cast4(const float* __restrict__ s0,
                                               const float* __restrict__ s1,
                                               const float* __restrict__ s2,
                                               const float* __restrict__ s3,
                                               unsigned short* __restrict__ d0,
                                               unsigned short* __restrict__ d1,
                                               unsigned short* __restrict__ d2,
                                               unsigned short* __restrict__ d3) {
  const float* src = (blockIdx.y == 0) ? s0 : (blockIdx.y == 1) ? s1
                     : (blockIdx.y == 2) ? s2 : s3;
  unsigned short* dst = (blockIdx.y == 0) ? d0 : (blockIdx.y == 1) ? d1
                        : (blockIdx.y == 2) ? d2 : d3;
  int i = (blockIdx.x * 256 + threadIdx.x) * 4;
  float4 v = *(const float4*)&src[i];
  u16x4 o = {f2bf(v.x), f2bf(v.y), f2bf(v.z), f2bf(v.w)};
  *(u16x4*)&dst[i] = o;
}

#define GBM 128
#define GBN 128
#define GBK 32

// ---------------------------------------------------------------------------
// Fused K+V projection GEMM. 512 threads = 8 waves; waves 0-3: K tile (2x2),
// waves 4-7: V tile. A staged once per K-step for both outputs.
// 3-buffer, SINGLE barrier per K-step. T2 swizzle + T5 setprio.
__global__ __launch_bounds__(512) void k_gemm_kv(const unsigned short* __restrict__ A,
                                                 const unsigned short* __restrict__ Bk,
                                                 const unsigned short* __restrict__ Bv,
                                                 const float* __restrict__ bk,
                                                 const float* __restrict__ bv,
                                                 unsigned short* __restrict__ Ko,
                                                 unsigned short* __restrict__ Vo,
                                                 int M, int K) {
  __shared__ __attribute__((aligned(16))) unsigned short smem[3][3 * GBM * GBK]; // 72 KB
  int w = blockIdx.x;
  int nbm = gridDim.x >> 3;                  // 130
  int t = (w >> 3) + (w & 7) * nbm;          // contiguous t per XCD
  int bm = (t >> 3) * GBM;
  int bn = (t & 7) * GBN;
  int tid = threadIdx.x;
  int wid = tid >> 6, lane = tid & 63;
  int w2 = wid & 3;
  int wr = w2 >> 1, wc = w2 & 1;
  int fq = lane >> 4, fr = lane & 15;
  int srow = lane >> 2;
  int scol = (((lane & 3) ^ ((lane >> 3) & 3)) * 8);   // pre-swizzled source col
  int sslot = (fq ^ ((fr >> 1) & 3)) * 8;              // swizzled read slot
  int boff = (wid < 4) ? GBM * GBK : 2 * GBM * GBK;

  auto stage = [&](int buf, int k0) {
    #pragma unroll
    for (int i = 0; i < 3; i++) {
      int ci = wid * 3 + i;                  // 0..23 chunks of 1 KB (16 rows)
      const unsigned short* src;
      if (ci < 8) {
        int gA = bm + ci * 16 + srow; if (gA > M - 1) gA = M - 1;
        src = A + (size_t)gA * K + k0 + scol;
      } else if (ci < 16) {
        src = Bk + (size_t)(bn + (ci - 8) * 16 + srow) * K + k0 + scol;
      } else {
        src = Bv + (size_t)(bn + (ci - 16) * 16 + srow) * K + k0 + scol;
      }
      __builtin_amdgcn_global_load_lds(
          (const __attribute__((address_space(1))) void*)src,
          (__attribute__((address_space(3))) void*)((char*)&smem[buf][0] + ci * 1024),
          16, 0, 0);
    }
  };

  f32x4 acc[4][4] = {};
  const int NT = K / GBK;                    // 32
  stage(0, 0);
  stage(1, GBK);
  for (int it = 0; it < NT; it++) {
    int cur = it % 3;
    asm volatile("" ::: "memory");
    __builtin_amdgcn_s_barrier();            // all compute(it-1) reads done
    asm volatile("" ::: "memory");
    if (it + 2 < NT) {
      stage((it + 2) % 3, (it + 2) * GBK);
      asm volatile("s_waitcnt vmcnt(6)" ::: "memory");
    } else if (it + 1 < NT) {
      asm volatile("s_waitcnt vmcnt(3)" ::: "memory");
    } else {
      asm volatile("s_waitcnt vmcnt(0)" ::: "memory");
    }
    const unsigned short (*As)[GBK]  = (const unsigned short (*)[GBK])(&smem[cur][0]);
    const unsigned short (*Bts)[GBK] = (const unsigned short (*)[GBK])(&smem[cur][0] + boff);
    bf16x8 af[4], bfr[4];
    #pragma unroll
    for (int mi = 0; mi < 4; mi++)
      af[mi] = *(const bf16x8*)&As[wr * 64 + mi * 16 + fr][sslot];
    #pragma unroll
    for (int ni = 0; ni < 4; ni++)
      bfr[ni] = *(const bf16x8*)&Bts[wc * 64 + ni * 16 + fr][sslot];
    __builtin_amdgcn_s_setprio(1);
    #pragma unroll
    for (int mi = 0; mi < 4; mi++)
      #pragma unroll
      for (int ni = 0; ni < 4; ni++)
        acc[mi][ni] = __builtin_amdgcn_mfma_f32_16x16x32_bf16(bfr[ni], af[mi], acc[mi][ni], 0, 0, 0);
    __builtin_amdgcn_s_setprio(0);
  }
  // Swapped layout: lane value j -> n = bn + wc*64 + ni*16 + fq*4 + j,
  //                 m = bm + wr*64 + mi*16 + fr.  (mi outer: line-adjacent stores)
  const float* bias = (wid < 4) ? bk : bv;
  unsigned short* Cout = (wid < 4) ? Ko : Vo;
  #pragma unroll
  for (int mi = 0; mi < 4; mi++) {
    int m = bm + wr * 64 + mi * 16 + fr;
    if (m >= M) continue;
    #pragma unroll
    for (int ni = 0; ni < 4; ni++) {
      int n0 = bn + wc * 64 + ni * 16 + fq * 4;
      float4 b4 = *(const float4*)&bias[n0];
      u16x4 o = {f2bf(acc[mi][ni][0] + b4.x), f2bf(acc[mi][ni][1] + b4.y),
                 f2bf(acc[mi][ni][2] + b4.z), f2bf(acc[mi][ni][3] + b4.w)};
      *(u16x4*)&Cout[(size_t)m * C_ + n0] = o;
    }
  }
}

// ---------------------------------------------------------------------------
// Split-K mean GEMM, 2-phase dbuf + T2 swizzle: A = msigbf [256][HW_], B = xbf.
__global__ __launch_bounds__(256) void k_gemm_meank(const unsigned short* __restrict__ A,
                                                    const unsigned short* __restrict__ B,
                                                    float* __restrict__ partial) {
  __shared__ __attribute__((aligned(16))) unsigned short As[2][GBM][GBK];
  __shared__ __attribute__((aligned(16))) unsigned short Bs[2][GBN][GBK];
  int bm = blockIdx.y * GBM, bn = blockIdx.x * GBN;
  int kc = blockIdx.z;
  int tid = threadIdx.x;
  int wid = tid >> 6, lane = tid & 63;
  int wr = wid >> 1, wc = wid & 1;
  int fq = lane >> 4, fr = lane & 15;
  int srow = lane >> 2;
  int scol = (((lane & 3) ^ ((lane >> 3) & 3)) * 8);
  int sslot = (fq ^ ((fr >> 1) & 3)) * 8;

  auto stage = [&](int buf, int k0) {
    #pragma unroll
    for (int i = 0; i < 2; i++) {
      int r = wid * 32 + i * 16 + srow;
      __builtin_amdgcn_global_load_lds(
          (const __attribute__((address_space(1))) void*)(A + (size_t)(bm + r) * HW_ + k0 + scol),
          (__attribute__((address_space(3))) void*)((char*)&As[buf][0][0] + (wid * 2 + i) * 1024),
          16, 0, 0);
      __builtin_amdgcn_global_load_lds(
          (const __attribute__((address_space(1))) void*)(B + (size_t)(bn + r) * HW_ + k0 + scol),
          (__attribute__((address_space(3))) void*)((char*)&Bs[buf][0][0] + (wid * 2 + i) * 1024),
          16, 0, 0);
    }
  };

  f32x4 acc[4][4] = {};
  int kbeg = kc * KCH;
  const int NT = KCH / GBK;
  stage(0, kbeg);
  __syncthreads();
  int cur = 0;
  for (int it = 0; it < NT; it++) {
    if (it + 1 < NT) stage(cur ^ 1, kbeg + (it + 1) * GBK);
    bf16x8 af[4], bfr[4];
    #pragma unroll
    for (int mi = 0; mi < 4; mi++)
      af[mi] = *(const bf16x8*)&As[cur][wr * 64 + mi * 16 + fr][sslot];
    #pragma unroll
    for (int ni = 0; ni < 4; ni++)
      bfr[ni] = *(const bf16x8*)&Bs[cur][wc * 64 + ni * 16 + fr][sslot];
    #pragma unroll
    for (int mi = 0; mi < 4; mi++)
      #pragma unroll
      for (int ni = 0; ni < 4; ni++)
        acc[mi][ni] = __builtin_amdgcn_mfma_f32_16x16x32_bf16(bfr[ni], af[mi], acc[mi][ni], 0, 0, 0);
    __syncthreads();
    cur ^= 1;
  }
  #pragma unroll
  for (int mi = 0; mi < 4; mi++) {
    int m = bm + wr * 64 + mi * 16 + fr;
    #pragma unroll
    for (int ni = 0; ni < 4; ni++) {
      int n0 = bn + wc * 64 + ni * 16 + fq * 4;
      *(f32x4*)&partial[((size_t)kc * 256 + m) * C_ + n0] = acc[mi][ni];
    }
  }
}

// ---------------------------------------------------------------------------
// mean = (sum of partials) / (w + 1e-3) -> seqbf rows 0..Q-1 (bf16)
__global__ __launch_bounds__(256) void k_mean_reduce(const float* __restrict__ partial,
                                                     const float* __restrict__ w,
                                                     unsigned short* __restrict__ seqbf) {
  int m = blockIdx.x;  // 0..Q_-1
  float rs = 1.f / (w[m] + 0.001f);
  for (int n = threadIdx.x; n < C_; n += 256) {
    float s = 0.f;
    #pragma unroll
    for (int kc = 0; kc < KSPLIT; kc++)
      s += partial[((size_t)kc * 256 + m) * C_ + n];
    seqbf[(size_t)m * C_ + n] = f2bf(s * rs);
  }
}

// ---------------------------------------------------------------------------
// Split-K bf16 MFMA GEMM for small-M projections, 2-phase + T2 swizzle.
__global__ __launch_bounds__(256) void k_gemm_splitk_bf(const unsigned short* __restrict__ A,
                                                        const unsigned short* __restrict__ B,
                                                        float* __restrict__ partial,
                                                        int M, int K) {
  __shared__ __attribute__((aligned(16))) unsigned short As[2][GBM][GBK];
  __shared__ __attribute__((aligned(16))) unsigned short Bs[2][GBN][GBK];
  int bm = blockIdx.y * GBM, bn = blockIdx.x * GBN;
  int kc = blockIdx.z;
  int kchunk = K / SK;
  int tid = threadIdx.x;
  int wid = tid >> 6, lane = tid & 63;
  int wr = wid >> 1, wc = wid & 1;
  int fq = lane >> 4, fr = lane & 15;
  int srow = lane >> 2;
  int scol = (((lane & 3) ^ ((lane >> 3) & 3)) * 8);
  int sslot = (fq ^ ((fr >> 1) & 3)) * 8;

  auto stage = [&](int buf, int k0) {
    #pragma unroll
    for (int i = 0; i < 2; i++) {
      int r = wid * 32 + i * 16 + srow;
      int gA = bm + r; if (gA > M - 1) gA = M - 1;
      __builtin_amdgcn_global_load_lds(
          (const __attribute__((address_space(1))) void*)(A + (size_t)gA * K + k0 + scol),
          (__attribute__((address_space(3))) void*)((char*)&As[buf][0][0] + (wid * 2 + i) * 1024),
          16, 0, 0);
      __builtin_amdgcn_global_load_lds(
          (const __attribute__((address_space(1))) void*)(B + (size_t)(bn + r) * K + k0 + scol),
          (__attribute__((address_space(3))) void*)((char*)&Bs[buf][0][0] + (wid * 2 + i) * 1024),
          16, 0, 0);
    }
  };

  f32x4 acc[4][4] = {};
  int kbeg = kc * kchunk;
  const int NT = kchunk / GBK;
  stage(0, kbeg);
  __syncthreads();
  int cur = 0;
  for (int it = 0; it < NT; it++) {
    if (it + 1 < NT) stage(cur ^ 1, kbeg + (it + 1) * GBK);
    bf16x8 af[4], bfr[4];
    #pragma unroll
    for (int mi = 0; mi < 4; mi++)
      af[mi] = *(const bf16x8*)&As[cur][wr * 64 + mi * 16 + fr][sslot];
    #pragma unroll
    for (int ni = 0; ni < 4; ni++)
      bfr[ni] = *(const bf16x8*)&Bs[cur][wc * 64 + ni * 16 + fr][sslot];
    #pragma unroll
    for (int mi = 0; mi < 4; mi++)
      #pragma unroll
      for (int ni = 0; ni < 4; ni++)
        acc[mi][ni] = __builtin_amdgcn_mfma_f32_16x16x32_bf16(bfr[ni], af[mi], acc[mi][ni], 0, 0, 0);
    __syncthreads();
    cur ^= 1;
  }
  #pragma unroll
  for (int mi = 0; mi < 4; mi++) {
    int m = bm + wr * 64 + mi * 16 + fr;
    #pragma unroll
    for (int ni = 0; ni < 4; ni++) {
      int n0 = bn + wc * 64 + ni * 16 + fq * 4;
      *(f32x4*)&partial[((size_t)kc * 256 + m) * C_ + n0] = acc[mi][ni];
    }
  }
}

// ---------------------------------------------------------------------------
__global__ __launch_bounds__(256) void k_splitk_reduce(const float* __restrict__ partial,
                                                       const float* __restrict__ bias,
                                                       float* __restrict__ outf) {
  int m = blockIdx.x;
  for (int n = threadIdx.x; n < C_; n += 256) {
    float s = 0.f;
    #pragma unroll
    for (int kc = 0; kc < SK; kc++)
      s += partial[((size_t)kc * 256 + m) * C_ + n];
    outf[(size_t)m * C_ + n] = s + bias[n];
  }
}

// ---------------------------------------------------------------------------
// Sparse gather attention, split across ASPLIT blocks per (q,h).
// Q is read directly from the Q-projection's split-K partials (+bias) — the
// separate reduce kernel and qbuf roundtrip are folded in here.
__global__ __launch_bounds__(256) void k_attn_split(const float* __restrict__ qpart,
                                                    const float* __restrict__ bq,
                                                    const unsigned short* __restrict__ kb,
                                                    const unsigned short* __restrict__ vb,
                                                    const int* __restrict__ cnt_g,
                                                    const int* __restrict__ idxg,
                                                    float* __restrict__ pmax,
                                                    float* __restrict__ psum,
                                                    float* __restrict__ pacc) {
  int q = blockIdx.x, h = blockIdx.y, sp = blockIdx.z;
  int tid = threadIdx.x;
  int lane = tid & 63, wid = tid >> 6;

  __shared__ float qs[64];
  __shared__ float sc[CAP / ASPLIT];   // 128
  __shared__ int   ls[CAP / ASPLIT];
  __shared__ float wred[4];
  __shared__ float accb[4][64];

  int cnt = cnt_g[q];
  int cq = (cnt + ASPLIT - 1) / ASPLIT;
  int beg = sp * cq;
  int end = beg + cq; if (end > cnt) end = cnt;
  int ns = end - beg; if (ns < 0) ns = 0;

  if (tid < 64) {
    float s = bq[h * HD_ + tid];
    #pragma unroll
    for (int kc = 0; kc < SK; kc++)
      s += qpart[((size_t)kc * 256 + q) * C_ + h * HD_ + tid];
    qs[tid] = s * 0.125f;   // hd^-0.5
  }
  __syncthreads();

  // scores: row i handled by 4 lanes (16 dims each)
  for (int i0 = 0; i0 < ns; i0 += 64) {
    int i = i0 + (tid >> 2);
    if (i < ns) {
      int sub = tid & 3;
      int l = idxg[(size_t)q * CAP + beg + i];
      const u16x8* kr = (const u16x8*)(kb + (size_t)l * C_ + h * HD_ + sub * 16);
      u16x8 kv0 = kr[0], kv1 = kr[1];
      float s = 0.f;
      #pragma unroll
      for (int e = 0; e < 8; e++) s = fmaf(qs[sub * 16 + e], bf2f(kv0[e]), s);
      #pragma unroll
      for (int e = 0; e < 8; e++) s = fmaf(qs[sub * 16 + 8 + e], bf2f(kv1[e]), s);
      s += __shfl_xor(s, 1);
      s += __shfl_xor(s, 2);
      if (sub == 0) { sc[i] = s; ls[i] = l; }
    }
  }
  __syncthreads();

  float lm = (tid < ns) ? sc[tid] : -INFINITY;
  #pragma unroll
  for (int off = 32; off; off >>= 1) lm = fmaxf(lm, __shfl_xor(lm, off));
  if (lane == 0) wred[wid] = lm;
  __syncthreads();
  float m4 = fmaxf(fmaxf(wred[0], wred[1]), fmaxf(wred[2], wred[3]));

  float e = 0.f;
  if (tid < ns) {
    e = expf(sc[tid] - m4);
    sc[tid] = e;
  }
  float lsum = e;
  #pragma unroll
  for (int off = 32; off; off >>= 1) lsum += __shfl_xor(lsum, off);
  __syncthreads();
  if (lane == 0) wred[wid] = lsum;
  __syncthreads();
  float S4 = wred[0] + wred[1] + wred[2] + wred[3];

  float acc = 0.f;
  for (int j = wid; j < ns; j += 4)
    acc = fmaf(sc[j], bf2f(vb[(size_t)ls[j] * C_ + h * HD_ + lane]), acc);
  accb[wid][lane] = acc;
  __syncthreads();

  int pidx = (q * NH_ + h) * ASPLIT + sp;
  if (tid < 64)
    pacc[(size_t)pidx * 64 + tid] =
        accb[0][tid] + accb[1][tid] + accb[2][tid] + accb[3][tid];
  if (tid == 0) {
    pmax[pidx] = (ns > 0) ? m4 : -INFINITY;
    psum[pidx] = S4;
  }
}

// ---------------------------------------------------------------------------
__global__ __launch_bounds__(64) void k_attn_merge(const float* __restrict__ pmax,
                                                   const float* __restrict__ psum,
                                                   const float* __restrict__ pacc,
                                                   unsigned short* __restrict__ ctxbf) {
  int q = blockIdx.x, h = blockIdx.y;
  int d = threadIdx.x;
  int base = (q * NH_ + h) * ASPLIT;
  float M = -INFINITY;
  #pragma unroll
  for (int s = 0; s < ASPLIT; s++) M = fmaxf(M, pmax[base + s]);
  float S = 0.f, a = 0.f;
  #pragma unroll
  for (int s = 0; s < ASPLIT; s++) {
    float wgt = expf(pmax[base + s] - M);
    S += psum[base + s] * wgt;
    a += pacc[(size_t)(base + s) * 64 + d] * wgt;
  }
  ctxbf[(size_t)q * C_ + h * HD_ + d] = f2bf(a / S);
}

// ---------------------------------------------------------------------------
extern "C" void kernel_launch(void* const* d_in, const int* in_sizes, int n_in,
                              void* d_out, int out_size, void* d_ws, size_t ws_size,
                              hipStream_t stream) {
  const float* x     = (const float*)d_in[0];
  const float* masks = (const float*)d_in[1];
  const float* Wq    = (const float*)d_in[2];
  const float* bq    = (const float*)d_in[3];
  const float* Wk    = (const float*)d_in[4];
  const float* bk    = (const float*)d_in[5];
  const float* Wv    = (const float*)d_in[6];
  const float* bv    = (const float*)d_in[7];
  const float* Wc    = (const float*)d_in[8];
  const float* bc    = (const float*)d_in[9];
  float* out = (float*)d_out;

  char* p = (char*)d_ws;
  auto alloc = [&](size_t bytes) {
    char* r = p;
    p += (bytes + 255) & ~(size_t)255;
    return r;
  };
  float* w       = (float*)alloc(1024);
  float* partial = (float*)alloc((size_t)KSPLIT * 256 * C_ * 4);
  float* qpart   = (float*)alloc((size_t)SK * 256 * C_ * 4);
  int*   cnt     = (int*)alloc(1024);
  int*   idxg    = (int*)alloc((size_t)Q_ * CAP * 4);
  float* pmax    = (float*)alloc((size_t)Q_ * NH_ * ASPLIT * 4);
  float* psum    = (float*)alloc((size_t)Q_ * NH_ * ASPLIT * 4);
  float* pacc    = (float*)alloc((size_t)Q_ * NH_ * ASPLIT * 64 * 4);
  unsigned short* msigbf = (unsigned short*)alloc((size_t)256 * HW_ * 2);
  unsigned short* xbf    = (unsigned short*)alloc((size_t)C_ * HW_ * 2);
  unsigned short* seqbf  = (unsigned short*)alloc((size_t)L_ * C_ * 2);
  unsigned short* wkbf   = (unsigned short*)alloc((size_t)C_ * C_ * 2);
  unsigned short* wvbf   = (unsigned short*)alloc((size_t)C_ * C_ * 2);
  unsigned short* wqbf   = (unsigned short*)alloc((size_t)C_ * C_ * 2);
  unsigned short* wcbf   = (unsigned short*)alloc((size_t)C_ * C_ * 2);
  unsigned short* ctxbf  = (unsigned short*)alloc((size_t)256 * C_ * 2);
  unsigned short* kbuf   = (unsigned short*)alloc((size_t)L_ * C_ * 2);
  unsigned short* vbuf   = (unsigned short*)alloc((size_t)L_ * C_ * 2);

  k_sig_compact<<<256, 256, 0, stream>>>(masks, msigbf, w, cnt, idxg);
  k_xcast<<<dim3(HW_ / 32, C_ / 32), dim3(32, 8), 0, stream>>>(x, xbf, seqbf);
  k_cast4<<<dim3(C_ * C_ / 1024, 4), 256, 0, stream>>>(Wk, Wv, Wq, Wc,
                                                       wkbf, wvbf, wqbf, wcbf);
  // mean: split-K MFMA + reduce (writes seqbf rows 0..Q-1)
  k_gemm_meank<<<dim3(C_ / GBN, 2, KSPLIT), 256, 0, stream>>>(msigbf, xbf, partial);
  k_mean_reduce<<<Q_, 256, 0, stream>>>(partial, w, seqbf);
  // Q projection (bf16 split-K; reduce folded into attention)
  k_gemm_splitk_bf<<<dim3(C_ / GBN, 2, SK), 256, 0, stream>>>(seqbf, wqbf, qpart, Q_, C_);
  // Fused K+V projections (bf16 MFMA, bf16 outputs), XCD-local tile order
  k_gemm_kv<<<8 * ((L_ + GBM - 1) / GBM), 512, 0, stream>>>(
      seqbf, wkbf, wvbf, bk, bv, kbuf, vbuf, L_, C_);
  // sparse attention (split + merge -> ctxbf); Q read from qpart (+bq)
  k_attn_split<<<dim3(Q_, NH_, ASPLIT), 256, 0, stream>>>(
      qpart, bq, kbuf, vbuf, cnt, idxg, pmax, psum, pacc);
  k_attn_merge<<<dim3(Q_, NH_), 64, 0, stream>>>(pmax, psum, pacc, ctxbf);
  // output projection (bf16 split-K)
  k_gemm_splitk_bf<<<dim3(C_ / GBN, 2, SK), 256, 0, stream>>>(ctxbf, wcbf, partial, Q_, C_);
  k_splitk_reduce<<<Q_, 256, 0, stream>>>(partial, bc, out);
}